// Round 6
// baseline (282.522 us; speedup 1.0000x reference)
//
#include <hip/hip_runtime.h>
#include <hip/hip_bf16.h>
#include <cstdint>

// Problem constants (match reference)
#define B_SZ     256
#define D_DIM    2048
#define N_PROXY  16384
#define P_POS    4
#define K_SEL    54        // BG_KNN + P
#define TEMP_INV 20.0f     // 1/0.05

typedef __bf16 bf16_t;
typedef __bf16 bf16x4 __attribute__((ext_vector_type(4)));
typedef __bf16 bf16x8 __attribute__((ext_vector_type(8)));
typedef float  f32x4  __attribute__((ext_vector_type(4)));

// ---------------------------------------------------------------------------
// Kernel 0: F fp32 [256,2048] -> Fb bf16 in MFMA-A fragment-major layout.
// frag slot g = (mb16*64 + kt)*64 + lane holds A[m=mb16*16+(lane&15)]
// [k = kt*32 + (lane>>4)*8 + j], j=0..7.
// ---------------------------------------------------------------------------
__global__ __launch_bounds__(256)
void conv_feat(const float* __restrict__ F, bf16_t* __restrict__ Fb) {
    int g    = blockIdx.x * 256 + threadIdx.x;   // 0..65535
    int lane = g & 63;
    int kt   = (g >> 6) & 63;
    int mb   = g >> 12;                          // 0..15
    int frow = lane & 15;
    int quad = (lane >> 4) & 3;
    const float* src = F + (size_t)(mb * 16 + frow) * D_DIM + kt * 32 + quad * 8;
    float4 lo = *(const float4*)src;
    float4 hi = *(const float4*)(src + 4);
    bf16x8 o = { (bf16_t)lo.x, (bf16_t)lo.y, (bf16_t)lo.z, (bf16_t)lo.w,
                 (bf16_t)hi.x, (bf16_t)hi.y, (bf16_t)hi.z, (bf16_t)hi.w };
    *(bf16x8*)(Fb + (size_t)g * 8) = o;
}

// ---------------------------------------------------------------------------
// Kernel 1: Sb = bf16((F @ em.T)/TEMP).
// TLP design: wave tile 64x16 (acc=16 VGPR), block = 4 waves, SAME m-block,
// 4 consecutive 16-col n-stripes (A stream identical across waves -> L1 hit).
// Grid 1024 = 4 blocks/CU = 16 waves/CU (occupancy 50%) -> ~128 outstanding
// loads/CU hides latency by TLP, not compiler ILP (the r2-r5 failure).
// Zero __syncthreads in the K-loop (wave-private double-buffered B in LDS).
// Swizzle: the 4 m-blocks of one n-group sit 8 blocks apart = same XCD.
// ---------------------------------------------------------------------------
__global__ __launch_bounds__(256, 4)
void gemm_score(const bf16_t* __restrict__ Fb, const float* __restrict__ E,
                bf16_t* __restrict__ Sb) {
    const int gb   = blockIdx.x;
    const int mb   = (gb >> 3) & 3;              // m-block of 64 rows
    const int ng   = (gb & 7) | ((gb >> 5) << 3);// n-group of 64 cols (0..255)
    const int tid  = threadIdx.x;
    const int lane = tid & 63;
    const int wave = tid >> 6;                   // n-stripe of 16 within group
    const int frow = lane & 15;
    const int quad = (lane >> 4) & 3;

    // wave-private double-buffered B-fragment (512 bf16 = 1 KB each)
    __shared__ bf16_t Bls[4][2][512];

    f32x4 acc[4] = {};                           // [m], wave tile 64x16

    // ---- B staging: 16 rows x 32 fp32 per step = 128 float4, 2/lane.
    // slot s = j*64+lane: row = s>>3 (16 rows x 8 f4), c4 = (s&7)*4.
    const float* bsrc[2];
    int bdst[2];
#pragma unroll
    for (int j = 0; j < 2; ++j) {
        int s    = j * 64 + lane;
        int srow = s >> 3;
        int c4   = (s & 7) * 4;
        bsrc[j] = E + (size_t)(ng * 64 + wave * 16 + srow) * D_DIM + c4;
        bdst[j] = (srow + 16 * (c4 >> 3)) * 8 + (c4 & 7); // bf16 units
    }

    // A frag (m, kt) at Fb[((mb*4+m)*64 + kt)*512 + lane*8] (coalesced 1 KB)
    const bf16_t* Ab[4];
#pragma unroll
    for (int m = 0; m < 4; ++m)
        Ab[m] = Fb + ((size_t)((mb * 4 + m) * 64) * 512) + lane * 8;

    float4 Brg[2][2];      // B prefetch, 2 steps deep
    bf16x8 af[2][4];       // A frags, 1 step ahead

    bf16_t* lds = &Bls[wave][0][0];

    // ---- prologue: B(0),B(1) loads; A(0) loads; stage B(0) -> buf 0 ----
#pragma unroll
    for (int j = 0; j < 2; ++j) Brg[0][j] = *(const float4*)(bsrc[j]);
#pragma unroll
    for (int j = 0; j < 2; ++j) Brg[1][j] = *(const float4*)(bsrc[j] + 32);
#pragma unroll
    for (int m = 0; m < 4; ++m) af[0][m] = *(const bf16x8*)(Ab[m]);
#pragma unroll
    for (int j = 0; j < 2; ++j) {
        float4 v = Brg[0][j];
        bf16x4 h = { (bf16_t)v.x, (bf16_t)v.y, (bf16_t)v.z, (bf16_t)v.w };
        *(bf16x4*)(lds + bdst[j]) = h;
    }

#pragma unroll 4
    for (int kt = 0; kt < 64; ++kt) {
        const int cur = kt & 1, nxt = 1 - cur;
        // load B(kt+2) into the slot whose content (B(kt)) is already staged
        if (kt + 2 < 64) {
#pragma unroll
            for (int j = 0; j < 2; ++j)
                Brg[cur][j] = *(const float4*)(bsrc[j] + (kt + 2) * 32);
        }
        // load A(kt+1)
        if (kt + 1 < 64) {
#pragma unroll
            for (int m = 0; m < 4; ++m)
                af[nxt][m] = *(const bf16x8*)(Ab[m] + (kt + 1) * 512);
        }
        // compute on current buffer
        bf16x8 bg = *(const bf16x8*)(lds + cur * 512 + lane * 8);
#pragma unroll
        for (int m = 0; m < 4; ++m)
            acc[m] = __builtin_amdgcn_mfma_f32_16x16x32_bf16(
                af[cur][m], bg, acc[m], 0, 0, 0);
        // stage B(kt+1) into the other buffer (wave-private, no barrier)
        if (kt + 1 < 64) {
#pragma unroll
            for (int j = 0; j < 2; ++j) {
                float4 v = Brg[nxt][j];
                bf16x4 h = { (bf16_t)v.x, (bf16_t)v.y,
                             (bf16_t)v.z, (bf16_t)v.w };
                *(bf16x4*)(lds + nxt * 512 + bdst[j]) = h;
            }
        }
    }

    // ---- epilogue: C/D layout col=lane&15, row=quad*4+i; fold 1/TEMP ----
    const int gc = ng * 64 + wave * 16 + frow;
#pragma unroll
    for (int m = 0; m < 4; ++m) {
        int gr = mb * 64 + m * 16 + quad * 4;
#pragma unroll
        for (int i = 0; i < 4; ++i)
            Sb[(size_t)(gr + i) * N_PROXY + gc] =
                (bf16_t)(acc[m][i] * TEMP_INV);
    }
}

// ---------------------------------------------------------------------------
// Kernel 2: per-row top-K + log-softmax loss on bf16 scores.
// 512 threads/row, 32 keys/thread; 16-bit radix select with early exit.
// ---------------------------------------------------------------------------
__device__ __forceinline__ float key16_to_float(uint32_t k) {
    uint32_t bits16 = (k & 0x8000u) ? (k ^ 0x8000u) : ((~k) & 0xFFFFu);
    return __uint_as_float(bits16 << 16);
}

__device__ __forceinline__ int block_sum_i(int v, int tid, volatile int* rbuf) {
#pragma unroll
    for (int o = 32; o > 0; o >>= 1) v += __shfl_down(v, o, 64);
    __syncthreads();
    if ((tid & 63) == 0) rbuf[tid >> 6] = v;
    __syncthreads();
    int s = 0;
#pragma unroll
    for (int w = 0; w < 8; ++w) s += rbuf[w];
    return s;
}

__device__ __forceinline__ float block_sum_f(float v, int tid, volatile float* rbuf) {
#pragma unroll
    for (int o = 32; o > 0; o >>= 1) v += __shfl_down(v, o, 64);
    __syncthreads();
    if ((tid & 63) == 0) rbuf[tid >> 6] = v;
    __syncthreads();
    float s = 0.0f;
#pragma unroll
    for (int w = 0; w < 8; ++w) s += rbuf[w];
    return s;
}

__device__ __forceinline__ uint32_t block_max_u(uint32_t v, int tid,
                                                volatile uint32_t* rbuf) {
#pragma unroll
    for (int o = 32; o > 0; o >>= 1) {
        uint32_t w = __shfl_down(v, o, 64);
        v = (w > v) ? w : v;
    }
    __syncthreads();
    if ((tid & 63) == 0) rbuf[tid >> 6] = v;
    __syncthreads();
    uint32_t r = 0;
#pragma unroll
    for (int w = 0; w < 8; ++w) r = rbuf[w] > r ? rbuf[w] : r;
    return r;
}

__global__ __launch_bounds__(512)
void topk_loss(const bf16_t* __restrict__ S, const int* __restrict__ targets,
               const int* __restrict__ plabel, const int* __restrict__ ptable,
               float* __restrict__ out) {
    const int b    = blockIdx.x;
    const int tid  = threadIdx.x;
    const int lane = tid & 63;
    const int wave = tid >> 6;

    __shared__ int      sh_pos[4];
    __shared__ float    sh_pv[4];
    __shared__ int      sh_d;
    __shared__ int      rbuf_i[8];
    __shared__ float    rbuf_f[8];
    __shared__ uint32_t rbuf_u[8];
    __shared__ uint32_t cand_ls[64];
    __shared__ int      candcnt;
    __shared__ float    sh_numbg;

    const bf16_t* row = S + (size_t)b * N_PROXY;

    if (tid == 0) {
        int t  = targets[b];
        int py = plabel[t];
        int pos[4]; int d = 0;
        for (int j = 0; j < 4; ++j) {
            int p = ptable[py * 4 + j];
            bool dup = false;
            for (int i = 0; i < d; ++i) dup = dup || (pos[i] == p);
            if (!dup) pos[d++] = p;
        }
        sh_d = d;
        for (int j = 0; j < 4; ++j) sh_pos[j] = (j < d) ? pos[j] : -1;
        for (int j = 0; j < 4; ++j) sh_pv[j]  = (j < d) ? (float)row[pos[j]] : 0.0f;
        candcnt = 0;
    }
    __syncthreads();

    const int d  = sh_d;
    const int p0 = sh_pos[0], p1 = sh_pos[1], p2 = sh_pos[2], p3 = sh_pos[3];
    float pv[4];
#pragma unroll
    for (int j = 0; j < 4; ++j) pv[j] = sh_pv[j];

    // ---- 32 bf16 logits/thread as 16-bit sortable keys; positives -> 0 ----
    uint32_t keys[32];
#pragma unroll
    for (int j = 0; j < 4; ++j) {
        int g8 = j * 512 + tid;                     // 8-element granule
        ushort v[8];
        *(uint4*)v = *(const uint4*)(row + (size_t)g8 * 8);
#pragma unroll
        for (int q = 0; q < 8; ++q) {
            int idx = g8 * 8 + q;
            bool isp = (idx == p0) | (idx == p1) | (idx == p2) | (idx == p3);
            uint32_t bits = v[q];
            uint32_t key  = (bits & 0x8000u) ? ((~bits) & 0xFFFFu)
                                             : (bits | 0x8000u);
            keys[j * 8 + q] = isp ? 0u : key;
        }
    }

    const int need = K_SEL - d;              // backgrounds in the top-54 set

    // ---- 16-bit radix select with early exit ----
    uint32_t T = 0;
    for (int bit = 15; bit >= 0; --bit) {
        uint32_t cnd = T | (1u << bit);
        int c = 0;
#pragma unroll
        for (int j = 0; j < 32; ++j) c += (keys[j] >= cnd) ? 1 : 0;
        int ct = block_sum_i(c, tid, rbuf_i);
        if (ct >= need) {
            T = cnd;
            if (ct == need) break;           // selected set is exactly top-need
        }
    }
    const float vT = key16_to_float(T);

    // ---- stability max over backgrounds + positives ----
    uint32_t kmax = 0;
#pragma unroll
    for (int j = 0; j < 32; ++j) kmax = keys[j] > kmax ? keys[j] : kmax;
    kmax = block_max_u(kmax, tid, rbuf_u);
    float mx = key16_to_float(kmax);
    for (int j = 0; j < 4; ++j) if (j < d && pv[j] > mx) mx = pv[j];

    // ---- lse over selected set: strict-greater + exact tie fill + pos ----
    int c1 = 0; float se = 0.0f;
#pragma unroll
    for (int j = 0; j < 32; ++j) {
        if (keys[j] > T) { c1 += 1; se += __expf(key16_to_float(keys[j]) - mx); }
    }
    int   c1t = block_sum_i(c1, tid, rbuf_i);
    float set = block_sum_f(se, tid, rbuf_f);
    set += (float)(need - c1t) * __expf(vT - mx);
    for (int j = 0; j < 4; ++j) if (j < d) set += __expf(pv[j] - mx);
    const float lse = mx + logf(set);

    // ---- numerator: distinct positives + top (P-d) background values ----
    float num = 0.0f;
    for (int j = 0; j < 4; ++j) if (j < d) num += pv[j];
    if (d < P_POS) {
#pragma unroll
        for (int j = 0; j < 32; ++j) {
            if (keys[j] > T) {
                int p = atomicAdd(&candcnt, 1);
                cand_ls[p] = keys[j];
            }
        }
        __syncthreads();
        if (wave == 0) {
            const int cc = candcnt;
            uint32_t v = (lane < cc) ? cand_ls[lane] : T;   // pad with T (exact)
            float s = 0.0f;
            const int need2 = P_POS - d;                    // 1..3
            for (int it = 0; it < need2; ++it) {
                uint32_t m = v;
#pragma unroll
                for (int o = 32; o > 0; o >>= 1) {
                    uint32_t w = __shfl_xor(m, o, 64);
                    m = (w > m) ? w : m;
                }
                s += key16_to_float(m);
                unsigned long long msk = __ballot(v == m);
                int first = __ffsll(msk) - 1;
                if (lane == first) v = 0u;
            }
            if (lane == 0) sh_numbg = s;
        }
        __syncthreads();
        num += sh_numbg;
    }

    const float loss_b = lse - num * (1.0f / P_POS);
    if (tid == 0) atomicAdd(out, loss_b * (1.0f / B_SZ));
}

// ---------------------------------------------------------------------------
extern "C" void kernel_launch(void* const* d_in, const int* in_sizes, int n_in,
                              void* d_out, int out_size, void* d_ws, size_t ws_size,
                              hipStream_t stream) {
    const float* F       = (const float*)d_in[0];   // features [256,2048]
    const float* E       = (const float*)d_in[1];   // global_memory [16384,2048]
    const int*   targets = (const int*)d_in[2];     // [256]
    const int*   plabel  = (const int*)d_in[3];     // [32768]
    const int*   ptable  = (const int*)d_in[4];     // [4096,4]

    bf16_t* Fb = (bf16_t*)d_ws;                                     // 1 MB, frag-major
    bf16_t* Sb = (bf16_t*)((char*)d_ws + (size_t)B_SZ * D_DIM * 2); // 8 MB
    float*  out = (float*)d_out;

    hipMemsetAsync(d_out, 0, sizeof(float), stream);

    hipLaunchKernelGGL(conv_feat, dim3(256), dim3(256), 0, stream, F, Fb);
    hipLaunchKernelGGL(gemm_score, dim3(1024), dim3(256), 0, stream,
                       Fb, E, Sb);
    hipLaunchKernelGGL(topk_loss, dim3(B_SZ), dim3(512), 0, stream,
                       Sb, targets, plabel, ptable, out);
}

// Round 7
// 256.126 us; speedup vs baseline: 1.1031x; 1.1031x over previous
//
#include <hip/hip_runtime.h>
#include <hip/hip_bf16.h>
#include <cstdint>

// Problem constants (match reference)
#define B_SZ     256
#define D_DIM    2048
#define N_PROXY  16384
#define P_POS    4
#define K_SEL    54        // BG_KNN + P
#define TEMP_INV 20.0f     // 1/0.05

typedef __bf16 bf16_t;
typedef __bf16 bf16x4 __attribute__((ext_vector_type(4)));
typedef __bf16 bf16x8 __attribute__((ext_vector_type(8)));
typedef float  f32x4  __attribute__((ext_vector_type(4)));

// async global->LDS DMA, 16 B per lane; dest = lds_base + lane*16 (HW-fixed)
#define GLD_LDS16(g, l)                                                        \
    __builtin_amdgcn_global_load_lds(                                          \
        (const __attribute__((address_space(1))) void*)(g),                    \
        (__attribute__((address_space(3))) void*)(l), 16, 0, 0)

// ---------------------------------------------------------------------------
// Kernel 0: F fp32 [256,2048] -> Fb bf16 in MFMA-A fragment-major layout.
// frag slot g = (mb16*64 + kt)*64 + lane holds A[m=mb16*16+(lane&15)]
// [k = kt*32 + (lane>>4)*8 + j], j=0..7.
// ---------------------------------------------------------------------------
__global__ __launch_bounds__(256)
void conv_feat(const float* __restrict__ F, bf16_t* __restrict__ Fb) {
    int g    = blockIdx.x * 256 + threadIdx.x;   // 0..65535
    int lane = g & 63;
    int kt   = (g >> 6) & 63;
    int mb   = g >> 12;                          // 0..15
    int frow = lane & 15;
    int quad = (lane >> 4) & 3;
    const float* src = F + (size_t)(mb * 16 + frow) * D_DIM + kt * 32 + quad * 8;
    float4 lo = *(const float4*)src;
    float4 hi = *(const float4*)(src + 4);
    bf16x8 o = { (bf16_t)lo.x, (bf16_t)lo.y, (bf16_t)lo.z, (bf16_t)lo.w,
                 (bf16_t)hi.x, (bf16_t)hi.y, (bf16_t)hi.z, (bf16_t)hi.w };
    *(bf16x8*)(Fb + (size_t)g * 8) = o;
}

// ---------------------------------------------------------------------------
// Kernel 1: Sb = bf16((F @ em.T)/TEMP).  m97-style K-loop: B staged by
// global_load_lds (DMA, no VGPRs -> compiler cannot collapse the pipeline,
// the r2-r6 failure), double-buffered LDS, ONE barrier per K-step.
// BN=32 (grid 512 = 2 blocks/CU: one block computes while the other drains
// its barrier). 4 waves; wave tile 64m x 32n; BK=32.
// B rows are XOR-swizzled chunk-wise AT THE SOURCE (DMA dest is lane-fixed,
// so the permutation goes into the per-lane global address) so that the
// column-pattern ds_reads hit all 8 chunk slots -> 2-way (free) conflicts.
// ---------------------------------------------------------------------------
__global__ __launch_bounds__(256, 2)
void gemm_score(const bf16_t* __restrict__ Fb, const float* __restrict__ E,
                bf16_t* __restrict__ Sb) {
    const int tid  = threadIdx.x;
    const int bn   = blockIdx.x;          // 32-row stripe of em
    const int lane = tid & 63;
    const int wave = tid >> 6;            // m-block (64 rows of F)
    const int frow = lane & 15;
    const int quad = (lane >> 4) & 3;

    // [buf][row][8 chunk-slots x 4 floats]; stored chunk slot s of row r
    // holds global chunk (s ^ (r&7)).
    __shared__ float Bs[2][32 * 32];      // 2 x 4 KB

    f32x4 acc[4][2] = {};                 // [m][n]

    // ---- DMA source: wave stages rows wave*8..+7. lane l -> row_loc=l>>3,
    // dest chunk slot l&7; source global chunk = (l&7) ^ row_loc.
    const int rloc = lane >> 3;
    const int csw  = ((lane & 7) ^ rloc) * 4;      // swizzled float col
    const float* gsrc = E + (size_t)(bn * 32 + wave * 8 + rloc) * D_DIM + csw;
    float* ldst0 = &Bs[0][wave * 256];             // wave-uniform dest base
    float* ldst1 = &Bs[1][wave * 256];

    // ---- A frags: frag-major Fb, frag (m,kt) at ((wave*4+m)*64+kt)*512 ----
    const bf16_t* Ab[4];
#pragma unroll
    for (int m = 0; m < 4; ++m)
        Ab[m] = Fb + ((size_t)((wave * 4 + m) * 64) * 512) + lane * 8;

    bf16x8 af[2][4];

    // ---- prologue: stage kt=0 -> buf0; A(0) ----
    GLD_LDS16(gsrc, ldst0);
#pragma unroll
    for (int m = 0; m < 4; ++m) af[0][m] = *(const bf16x8*)(Ab[m]);

    // B-frag read slots (swizzle-aware), frag n: row r=n*16+frow,
    // chunks 2q and 2q+1 live at slots (2q)^(frow&7), (2q+1)^(frow&7).
    const int r7   = frow & 7;
    const int s0   = ((quad * 2) ^ r7) * 4;        // float offset of chunk lo
    const int s1   = ((quad * 2 + 1) ^ r7) * 4;    // float offset of chunk hi

#pragma unroll 8
    for (int kt = 0; kt < 64; ++kt) {
        const int cur = kt & 1;
        __syncthreads();   // drains DMA+loads issued last iter: buf cur ready
        if (kt + 1 < 64) {
            GLD_LDS16(gsrc + (kt + 1) * 32, (cur ? ldst0 : ldst1));
#pragma unroll
            for (int m = 0; m < 4; ++m)
                af[1 - cur][m] = *(const bf16x8*)(Ab[m] + (kt + 1) * 512);
        }
        // ---- B frags from LDS (fp32, swizzled) -> bf16 ----
        bf16x8 bg[2];
#pragma unroll
        for (int n = 0; n < 2; ++n) {
            const float* p = &Bs[cur][(n * 16 + frow) * 32];
            f32x4 lo = *(const f32x4*)(p + s0);
            f32x4 hi = *(const f32x4*)(p + s1);
            bg[n] = (bf16x8){ (bf16_t)lo[0], (bf16_t)lo[1], (bf16_t)lo[2],
                              (bf16_t)lo[3], (bf16_t)hi[0], (bf16_t)hi[1],
                              (bf16_t)hi[2], (bf16_t)hi[3] };
        }
#pragma unroll
        for (int m = 0; m < 4; ++m)
#pragma unroll
            for (int n = 0; n < 2; ++n)
                acc[m][n] = __builtin_amdgcn_mfma_f32_16x16x32_bf16(
                    af[cur][m], bg[n], acc[m][n], 0, 0, 0);
    }

    // ---- epilogue: C/D layout col=lane&15, row=quad*4+i; fold 1/TEMP ----
#pragma unroll
    for (int m = 0; m < 4; ++m) {
        int gr = wave * 64 + m * 16 + quad * 4;
#pragma unroll
        for (int n = 0; n < 2; ++n) {
            int gc = bn * 32 + n * 16 + frow;
#pragma unroll
            for (int i = 0; i < 4; ++i)
                Sb[(size_t)(gr + i) * N_PROXY + gc] =
                    (bf16_t)(acc[m][n][i] * TEMP_INV);
        }
    }
}

// ---------------------------------------------------------------------------
// Kernel 2: per-row top-K + log-softmax loss on bf16 scores.
// 512 threads/row, 32 keys/thread; 16-bit radix select with early exit.
// ---------------------------------------------------------------------------
__device__ __forceinline__ float key16_to_float(uint32_t k) {
    uint32_t bits16 = (k & 0x8000u) ? (k ^ 0x8000u) : ((~k) & 0xFFFFu);
    return __uint_as_float(bits16 << 16);
}

__device__ __forceinline__ int block_sum_i(int v, int tid, volatile int* rbuf) {
#pragma unroll
    for (int o = 32; o > 0; o >>= 1) v += __shfl_down(v, o, 64);
    __syncthreads();
    if ((tid & 63) == 0) rbuf[tid >> 6] = v;
    __syncthreads();
    int s = 0;
#pragma unroll
    for (int w = 0; w < 8; ++w) s += rbuf[w];
    return s;
}

__device__ __forceinline__ float block_sum_f(float v, int tid, volatile float* rbuf) {
#pragma unroll
    for (int o = 32; o > 0; o >>= 1) v += __shfl_down(v, o, 64);
    __syncthreads();
    if ((tid & 63) == 0) rbuf[tid >> 6] = v;
    __syncthreads();
    float s = 0.0f;
#pragma unroll
    for (int w = 0; w < 8; ++w) s += rbuf[w];
    return s;
}

__device__ __forceinline__ uint32_t block_max_u(uint32_t v, int tid,
                                                volatile uint32_t* rbuf) {
#pragma unroll
    for (int o = 32; o > 0; o >>= 1) {
        uint32_t w = __shfl_down(v, o, 64);
        v = (w > v) ? w : v;
    }
    __syncthreads();
    if ((tid & 63) == 0) rbuf[tid >> 6] = v;
    __syncthreads();
    uint32_t r = 0;
#pragma unroll
    for (int w = 0; w < 8; ++w) r = rbuf[w] > r ? rbuf[w] : r;
    return r;
}

__global__ __launch_bounds__(512)
void topk_loss(const bf16_t* __restrict__ S, const int* __restrict__ targets,
               const int* __restrict__ plabel, const int* __restrict__ ptable,
               float* __restrict__ out) {
    const int b    = blockIdx.x;
    const int tid  = threadIdx.x;
    const int lane = tid & 63;
    const int wave = tid >> 6;

    __shared__ int      sh_pos[4];
    __shared__ float    sh_pv[4];
    __shared__ int      sh_d;
    __shared__ int      rbuf_i[8];
    __shared__ float    rbuf_f[8];
    __shared__ uint32_t rbuf_u[8];
    __shared__ uint32_t cand_ls[64];
    __shared__ int      candcnt;
    __shared__ float    sh_numbg;

    const bf16_t* row = S + (size_t)b * N_PROXY;

    if (tid == 0) {
        int t  = targets[b];
        int py = plabel[t];
        int pos[4]; int d = 0;
        for (int j = 0; j < 4; ++j) {
            int p = ptable[py * 4 + j];
            bool dup = false;
            for (int i = 0; i < d; ++i) dup = dup || (pos[i] == p);
            if (!dup) pos[d++] = p;
        }
        sh_d = d;
        for (int j = 0; j < 4; ++j) sh_pos[j] = (j < d) ? pos[j] : -1;
        for (int j = 0; j < 4; ++j) sh_pv[j]  = (j < d) ? (float)row[pos[j]] : 0.0f;
        candcnt = 0;
    }
    __syncthreads();

    const int d  = sh_d;
    const int p0 = sh_pos[0], p1 = sh_pos[1], p2 = sh_pos[2], p3 = sh_pos[3];
    float pv[4];
#pragma unroll
    for (int j = 0; j < 4; ++j) pv[j] = sh_pv[j];

    // ---- 32 bf16 logits/thread as 16-bit sortable keys; positives -> 0 ----
    uint32_t keys[32];
#pragma unroll
    for (int j = 0; j < 4; ++j) {
        int g8 = j * 512 + tid;                     // 8-element granule
        ushort v[8];
        *(uint4*)v = *(const uint4*)(row + (size_t)g8 * 8);
#pragma unroll
        for (int q = 0; q < 8; ++q) {
            int idx = g8 * 8 + q;
            bool isp = (idx == p0) | (idx == p1) | (idx == p2) | (idx == p3);
            uint32_t bits = v[q];
            uint32_t key  = (bits & 0x8000u) ? ((~bits) & 0xFFFFu)
                                             : (bits | 0x8000u);
            keys[j * 8 + q] = isp ? 0u : key;
        }
    }

    const int need = K_SEL - d;              // backgrounds in the top-54 set

    // ---- 16-bit radix select with early exit ----
    uint32_t T = 0;
    for (int bit = 15; bit >= 0; --bit) {
        uint32_t cnd = T | (1u << bit);
        int c = 0;
#pragma unroll
        for (int j = 0; j < 32; ++j) c += (keys[j] >= cnd) ? 1 : 0;
        int ct = block_sum_i(c, tid, rbuf_i);
        if (ct >= need) {
            T = cnd;
            if (ct == need) break;           // selected set is exactly top-need
        }
    }
    const float vT = key16_to_float(T);

    // ---- stability max over backgrounds + positives ----
    uint32_t kmax = 0;
#pragma unroll
    for (int j = 0; j < 32; ++j) kmax = keys[j] > kmax ? keys[j] : kmax;
    kmax = block_max_u(kmax, tid, rbuf_u);
    float mx = key16_to_float(kmax);
    for (int j = 0; j < 4; ++j) if (j < d && pv[j] > mx) mx = pv[j];

    // ---- lse over selected set: strict-greater + exact tie fill + pos ----
    int c1 = 0; float se = 0.0f;
#pragma unroll
    for (int j = 0; j < 32; ++j) {
        if (keys[j] > T) { c1 += 1; se += __expf(key16_to_float(keys[j]) - mx); }
    }
    int   c1t = block_sum_i(c1, tid, rbuf_i);
    float set = block_sum_f(se, tid, rbuf_f);
    set += (float)(need - c1t) * __expf(vT - mx);
    for (int j = 0; j < 4; ++j) if (j < d) set += __expf(pv[j] - mx);
    const float lse = mx + logf(set);

    // ---- numerator: distinct positives + top (P-d) background values ----
    float num = 0.0f;
    for (int j = 0; j < 4; ++j) if (j < d) num += pv[j];
    if (d < P_POS) {
#pragma unroll
        for (int j = 0; j < 32; ++j) {
            if (keys[j] > T) {
                int p = atomicAdd(&candcnt, 1);
                cand_ls[p] = keys[j];
            }
        }
        __syncthreads();
        if (wave == 0) {
            const int cc = candcnt;
            uint32_t v = (lane < cc) ? cand_ls[lane] : T;   // pad with T (exact)
            float s = 0.0f;
            const int need2 = P_POS - d;                    // 1..3
            for (int it = 0; it < need2; ++it) {
                uint32_t m = v;
#pragma unroll
                for (int o = 32; o > 0; o >>= 1) {
                    uint32_t w = __shfl_xor(m, o, 64);
                    m = (w > m) ? w : m;
                }
                s += key16_to_float(m);
                unsigned long long msk = __ballot(v == m);
                int first = __ffsll(msk) - 1;
                if (lane == first) v = 0u;
            }
            if (lane == 0) sh_numbg = s;
        }
        __syncthreads();
        num += sh_numbg;
    }

    const float loss_b = lse - num * (1.0f / P_POS);
    if (tid == 0) atomicAdd(out, loss_b * (1.0f / B_SZ));
}

// ---------------------------------------------------------------------------
extern "C" void kernel_launch(void* const* d_in, const int* in_sizes, int n_in,
                              void* d_out, int out_size, void* d_ws, size_t ws_size,
                              hipStream_t stream) {
    const float* F       = (const float*)d_in[0];   // features [256,2048]
    const float* E       = (const float*)d_in[1];   // global_memory [16384,2048]
    const int*   targets = (const int*)d_in[2];     // [256]
    const int*   plabel  = (const int*)d_in[3];     // [32768]
    const int*   ptable  = (const int*)d_in[4];     // [4096,4]

    bf16_t* Fb = (bf16_t*)d_ws;                                     // 1 MB, frag-major
    bf16_t* Sb = (bf16_t*)((char*)d_ws + (size_t)B_SZ * D_DIM * 2); // 8 MB
    float*  out = (float*)d_out;

    hipMemsetAsync(d_out, 0, sizeof(float), stream);

    hipLaunchKernelGGL(conv_feat, dim3(256), dim3(256), 0, stream, F, Fb);
    hipLaunchKernelGGL(gemm_score, dim3(N_PROXY / 32), dim3(256), 0, stream,
                       Fb, E, Sb);
    hipLaunchKernelGGL(topk_loss, dim3(B_SZ), dim3(512), 0, stream,
                       Sb, targets, plabel, ptable, out);
}